// Round 12
// baseline (131.878 us; speedup 1.0000x reference)
//
#include <hip/hip_runtime.h>
#include <hip/hip_bf16.h>

#define B_ 2
#define H_ 4
#define HD_ 32
#define NQ_ 2048
#define NKV_ 4096
#define DIM_ 128
#define SPAN_ 257
#define TABLE_ 66049
#define SCALE_ 0.17677669529663687f
#define LAMBDA_INIT_ 0.8f
#define DTHR 4.0f
#define CAPR 28

typedef float f32x4 __attribute__((ext_vector_type(4)));
typedef short s16x4 __attribute__((ext_vector_type(4)));
typedef short s16x8 __attribute__((ext_vector_type(8)));
typedef int   i32x4 __attribute__((ext_vector_type(4)));
typedef float fl4   __attribute__((ext_vector_type(4)));

static __device__ __forceinline__ unsigned short f2bf(float f) {
  unsigned u = __float_as_uint(f);
  u += 0x7FFFu + ((u >> 16) & 1u);
  return (unsigned short)(u >> 16);
}
static __device__ __forceinline__ unsigned cvtpk(float lo, float hi) {
  unsigned r;
  asm("v_cvt_pk_bf16_f32 %0, %1, %2" : "=v"(r) : "v"(lo), "v"(hi));
  return r;
}

// ---------------- prep: deterministic counting sort (by x) + rpe->bf16x4 ----------------
// (r11-validated verbatim: produces a bijection sorted by x)
__global__ __launch_bounds__(256) void prep(
    const int* __restrict__ cq, const int* __restrict__ ck,
    const float* __restrict__ rpe,
    int* __restrict__ cqs, int* __restrict__ cks,
    int* __restrict__ qperm, int* __restrict__ kperm,
    int* __restrict__ qrank, int* __restrict__ krank,
    uint2* __restrict__ rpeb) {
  const int tid = threadIdx.x;
  const int blk = blockIdx.x;
  if (blk >= 4) {
    int ci = (blk - 4) * 256 + tid;
    if (ci < TABLE_) {
      fl4 v = *(const fl4*)(rpe + 4 * ci);
      uint2 o;
      o.x = cvtpk(v[0], v[1]);
      o.y = cvtpk(v[2], v[3]);
      rpeb[ci] = o;
    }
    return;
  }
  const int b = blk >> 1;
  const bool isq = (blk & 1) == 0;
  const int N = isq ? NQ_ : NKV_;
  const int S = N >> 8;
  const int* src = (isq ? cq : ck) + b * N * 2;
  int* sc   = (isq ? cqs : cks) + b * N * 2;
  int* perm = (isq ? qperm : kperm) + b * N;
  int* rank = (isq ? qrank : krank) + b * N;

  __shared__ int xv[NKV_];
  __shared__ int hist[16][256];
  __shared__ int wavehist[4][256];
  __shared__ int pref[256];

  for (int i = tid; i < N; i += 256) xv[i] = src[2 * i];
  for (int i = tid; i < S * 256; i += 256) ((int*)hist)[i] = 0;
  __syncthreads();
  for (int s = 0; s < S; ++s) atomicAdd(&hist[s][xv[s * 256 + tid]], 1);
  __syncthreads();
  int tot = 0;
  for (int s = 0; s < S; ++s) tot += hist[s][tid];
  pref[tid] = tot;
  __syncthreads();
  if (tid == 0) {
    int run = 0;
    for (int i = 0; i < 256; ++i) { int t = pref[i]; pref[i] = run; run += t; }
  }
  __syncthreads();
  {
    int run = pref[tid];
    for (int s = 0; s < S; ++s) { int h = hist[s][tid]; hist[s][tid] = run; run += h; }
  }
  const int lane = tid & 63, w = tid >> 6;
  __syncthreads();
  for (int s = 0; s < S; ++s) {
    wavehist[w][lane] = 0; wavehist[w][64 + lane] = 0;
    wavehist[w][128 + lane] = 0; wavehist[w][192 + lane] = 0;
    int e = s * 256 + tid;
    int x = xv[e];
    unsigned long long m = ~0ull;
#pragma unroll
    for (int bit = 0; bit < 8; ++bit) {
      unsigned long long bl = __ballot((x >> bit) & 1);
      m &= ((x >> bit) & 1) ? bl : ~bl;
    }
    unsigned long long lt = (1ull << lane) - 1ull;
    int lrank = __popcll(m & lt);
    if ((m & lt) == 0ull) wavehist[w][x] = __popcll(m);
    __syncthreads();
    int offs = 0;
#pragma unroll
    for (int w2 = 0; w2 < 4; ++w2) if (w2 < w) offs += wavehist[w2][x];
    int r = hist[s][x] + offs + lrank;
    perm[r] = e;
    rank[e] = r;
    sc[2 * r] = x;
    sc[2 * r + 1] = src[2 * e + 1];
    __syncthreads();
  }
}

// ---------------- fused QKV projection: perm-gathered reads, LINEAR writes ----------------
// Row-gather reads stay coalesced (each source row = 512B contiguous); all
// writes use the r9-validated linear patterns.
__global__ __launch_bounds__(256) void qkv8g(
    const float* __restrict__ xq, const float* __restrict__ xkv,
    const float* __restrict__ Wq, const float* __restrict__ bq,
    const float* __restrict__ Wk, const float* __restrict__ bk,
    const float* __restrict__ Wv, const float* __restrict__ bv,
    const int* __restrict__ qperm, const int* __restrict__ kperm,
    unsigned short* __restrict__ Qb, unsigned short* __restrict__ Kb,
    unsigned short* __restrict__ Vsw) {
  const int idx = blockIdx.x;
  const bool isq = idx < 512;
  const int b  = isq ? (idx >> 8) : ((idx - 512) >> 9);
  const int n0 = isq ? ((idx & 255) * 8) : (((idx - 512) & 511) * 8);
  const float* xsrc = isq ? xq : xkv;
  const int* perm = (isq ? qperm + b * NQ_ : kperm + b * NKV_);
  const int nlen = isq ? NQ_ : NKV_;

  __shared__ __align__(16) float xr[8][DIM_];
  const int tid = threadIdx.x;
  {
    int rr = tid >> 5, c4 = tid & 31;
    int orig = perm[n0 + rr];
    *(fl4*)&xr[rr][c4 * 4] =
        *(const fl4*)(xsrc + ((size_t)b * nlen + orig) * DIM_ + c4 * 4);
  }
  __syncthreads();

  if (isq) {
    const int j = tid & 127, rh = tid >> 7;
    float acc[4];
    float bb = bq[j];
#pragma unroll
    for (int rr = 0; rr < 4; ++rr) acc[rr] = bb;
    for (int i4 = 0; i4 < 32; ++i4) {
      const float* wp = &Wq[(4 * i4) * DIM_ + j];
      float w0 = wp[0], w1 = wp[DIM_], w2 = wp[2 * DIM_], w3 = wp[3 * DIM_];
#pragma unroll
      for (int rr = 0; rr < 4; ++rr) {
        fl4 x4 = *(const fl4*)&xr[4 * rh + rr][4 * i4];
        acc[rr] = fmaf(x4[3], w3, fmaf(x4[2], w2, fmaf(x4[1], w1, fmaf(x4[0], w0, acc[rr]))));
      }
    }
    int h = j >> 5, d = j & 31;
    unsigned short* qb = Qb + (((size_t)b * H_ + h) * NQ_ + n0 + 4 * rh) * HD_ + d;
#pragma unroll
    for (int rr = 0; rr < 4; ++rr) qb[rr * HD_] = f2bf(acc[rr]);
  } else {
    const int half = tid >> 7, j = tid & 127;
    const float* W = half ? Wv : Wk;
    float bb = half ? bv[j] : bk[j];
    float acc[8];
#pragma unroll
    for (int rr = 0; rr < 8; ++rr) acc[rr] = bb;
    for (int i4 = 0; i4 < 32; ++i4) {
      const float* wp = &W[(4 * i4) * DIM_ + j];
      float w0 = wp[0], w1 = wp[DIM_], w2 = wp[2 * DIM_], w3 = wp[3 * DIM_];
#pragma unroll
      for (int rr = 0; rr < 8; ++rr) {
        fl4 x4 = *(const fl4*)&xr[rr][4 * i4];
        acc[rr] = fmaf(x4[3], w3, fmaf(x4[2], w2, fmaf(x4[1], w1, fmaf(x4[0], w0, acc[rr]))));
      }
    }
    int h = j >> 5, d = j & 31;
    if (half == 0) {
      unsigned short* kb2 = Kb + (((size_t)b * H_ + h) * NKV_ + n0) * HD_ + d;
#pragma unroll
      for (int rr = 0; rr < 8; ++rr) kb2[rr * HD_] = f2bf(acc[rr]);
    } else {
      unsigned short* vb = Vsw + (((size_t)b * H_ + h) * HD_ + d) * NKV_ + (n0 & ~31);
      const int base = n0 & 31;
#pragma unroll
      for (int c = 0; c < 2; ++c) {
        int k0r = base + 4 * c;
        int posb = (k0r < 16) ? 8 * (k0r >> 2) : 8 * ((k0r - 16) >> 2) + 4;
        s16x4 t4;
#pragma unroll
        for (int e = 0; e < 4; ++e) t4[e] = (short)f2bf(acc[4 * c + e]);
        *(s16x4*)(vb + posb) = t4;
      }
    }
  }
}

// ---------------- windowed differential flash-attention + out-proj ----------------
// Window bounds now computed from ACTUAL coord min/max (robust to sort-order
// imperfection); any dx outside the staged band falls back to the proven
// global gather. CAPR=28 -> ~61 KB LDS -> 2 blocks/CU.
__global__ __launch_bounds__(512) void attn_win(
    const unsigned short* __restrict__ Qg, const unsigned short* __restrict__ Kg,
    const unsigned short* __restrict__ Vg, const int* __restrict__ cqs,
    const int* __restrict__ cks, const int* __restrict__ qperm,
    const float* __restrict__ alpha, const uint2* __restrict__ rpeb,
    const float* __restrict__ rpe,
    const float* __restrict__ lq1, const float* __restrict__ lk1,
    const float* __restrict__ lq2, const float* __restrict__ lk2,
    const float* __restrict__ Wp, const float* __restrict__ bp,
    float* __restrict__ out) {

  const int tid = threadIdx.x;
  const int lane = tid & 63;
  const int wv = tid >> 6;
  const int qcol = lane & 15;
  const int g = lane >> 4;
  const int qt = blockIdx.x & 127;
  const int b = blockIdx.x >> 7;
  const int qg0 = qt * 16;

  __shared__ struct {
    union {
      float acc[3][8][16][36];
      float xq[16][128];
      uint2 wnd[CAPR * 257];
    } u;
    float mW[8][17];
    float lW[4][8][17];
    float wgt[8][17];
    float lam[2];
    int kbmin[8], kbmax[8];
  } S;

  if (tid < 2) {
    float s1 = 0.f, s2 = 0.f;
    for (int d = 0; d < HD_; ++d) {
      s1 += lq1[tid * HD_ + d] * lk1[tid * HD_ + d];
      s2 += lq2[tid * HD_ + d] * lk2[tid * HD_ + d];
    }
    S.lam[tid] = __expf(s1) - __expf(s2) + LAMBDA_INIT_;
  }

  s16x8 qf[4];
#pragma unroll
  for (int h = 0; h < 4; ++h)
    qf[h] = *(const s16x8*)(Qg + (((size_t)b * H_ + h) * NQ_ + qg0 + qcol) * HD_ + 8 * g);

  const int2* cq2 = (const int2*)cqs + (size_t)b * NQ_;
  const int2* ck2 = (const int2*)cks + (size_t)b * NKV_;
  const int2 cqv = cq2[qg0 + qcol];
  const int qx = cqv.x + 128, qy = cqv.y + 128;

  // true q-tile x-bounds (actual data, not order-dependent)
  int qminx = 1 << 30, qmaxx = -(1 << 30);
#pragma unroll
  for (int i = 0; i < 16; ++i) {
    int xq_ = cq2[qg0 + i].x;
    qminx = min(qminx, xq_);
    qmaxx = max(qmaxx, xq_);
  }

  const unsigned short* kb[4];
  const unsigned short* vp[4][2];
#pragma unroll
  for (int h = 0; h < 4; ++h) {
    kb[h] = Kg + (((size_t)b * H_ + h) * NKV_ + wv * 32) * HD_;
#pragma unroll
    for (int dt = 0; dt < 2; ++dt)
      vp[h][dt] = Vg + (((size_t)b * H_ + h) * HD_ + dt * 16 + qcol) * NKV_ + wv * 32 + 8 * g;
  }
  int koff[2];
#pragma unroll
  for (int t = 0; t < 2; ++t) koff[t] = (16 * t + qcol) * HD_ + 8 * g;

  const i32x4* ck4 = (const i32x4*)cks + (((size_t)b * NKV_ + wv * 32) >> 1);
  const fl4* __restrict__ rpe4 = (const fl4*)rpe;

  float m_run = -INFINITY;
  float l_run[4] = {0.f, 0.f, 0.f, 0.f};
  f32x4 z4 = {0.f, 0.f, 0.f, 0.f};
  f32x4 aS[4][2], aC[2][2];
#pragma unroll
  for (int h = 0; h < 4; ++h) { aS[h][0] = z4; aS[h][1] = z4; }
#pragma unroll
  for (int p = 0; p < 2; ++p) { aC[p][0] = z4; aC[p][1] = z4; }

  s16x8 kf[4][2], vf[4][2];
  i32x4 ckt[4];
  fl4 gB[8];

#define CKLD(ST) {                                                         \
    const int s_ = (ST);                                                   \
    _Pragma("unroll") for (int t = 0; t < 2; ++t)                          \
    _Pragma("unroll") for (int hf = 0; hf < 2; ++hf)                       \
      ckt[2 * t + hf] = ck4[s_ * 128 + 8 * t + 2 * g + hf];                \
  }
#define KLD(ST) {                                                          \
    const int s_ = (ST);                                                   \
    _Pragma("unroll") for (int h = 0; h < 4; ++h)                          \
    _Pragma("unroll") for (int t = 0; t < 2; ++t)                          \
      kf[h][t] = *(const s16x8*)(kb[h] + s_ * 256 * HD_ + koff[t]);        \
  }
#define VLD(ST) {                                                          \
    const int s_ = (ST);                                                   \
    _Pragma("unroll") for (int h = 0; h < 4; ++h)                          \
    _Pragma("unroll") for (int dt = 0; dt < 2; ++dt)                       \
      vf[h][dt] = *(const s16x8*)(vp[h][dt] + s_ * 256);                   \
  }
#define LGATH(DXLO, RR) {                                                  \
    _Pragma("unroll") for (int t = 0; t < 2; ++t)                          \
    _Pragma("unroll") for (int hf = 0; hf < 2; ++hf) {                     \
      i32x4 cc = ckt[2 * t + hf];                                          \
      _Pragma("unroll") for (int e = 0; e < 2; ++e) {                      \
        int dx = qx - cc[2 * e];     dx = dx < 0 ? 0 : (dx > 256 ? 256 : dx); \
        int dy = qy - cc[2 * e + 1]; dy = dy < 0 ? 0 : (dy > 256 ? 256 : dy); \
        int wr = dx - (DXLO);                                              \
        fl4 gg;                                                            \
        if (wr >= 0 && wr < (RR)) {                                        \
          uint2 wd = S.u.wnd[wr * 257 + dy];                               \
          gg[0] = __uint_as_float(wd.x << 16);                             \
          gg[1] = __uint_as_float(wd.x & 0xffff0000u);                     \
          gg[2] = __uint_as_float(wd.y << 16);                             \
          gg[3] = __uint_as_float(wd.y & 0xffff0000u);                     \
        } else {                                                           \
          gg = rpe4[dx * SPAN_ + dy];                                      \
        }                                                                  \
        gB[4 * t + 2 * hf + e] = gg;                                       \
      }                                                                    \
    }                                                                      \
  }

  CKLD(0);
  KLD(0);

  for (int s = 0; s < 16; ++s) {
    __syncthreads();   // previous supertile's window reads complete
    // true k-supertile x-bounds: wave-reduce actual coords (waves 0-3)
    {
      int mn = 1 << 30, mx = -(1 << 30);
      if (tid < 256) { int xk = ck2[s * 256 + tid].x; mn = xk; mx = xk; }
#pragma unroll
      for (int o = 32; o; o >>= 1) {
        mn = min(mn, __shfl_xor(mn, o));
        mx = max(mx, __shfl_xor(mx, o));
      }
      if (lane == 0) { S.kbmin[wv] = mn; S.kbmax[wv] = mx; }
    }
    __syncthreads();
    int kminx = min(min(S.kbmin[0], S.kbmin[1]), min(S.kbmin[2], S.kbmin[3]));
    int kmaxx = max(max(S.kbmax[0], S.kbmax[1]), max(S.kbmax[2], S.kbmax[3]));
    int dxlo = qminx + 128 - kmaxx; dxlo = dxlo < 0 ? 0 : (dxlo > 256 ? 256 : dxlo);
    int dxhi = qmaxx + 128 - kminx; dxhi = dxhi < 0 ? 0 : (dxhi > 256 ? 256 : dxhi);
    int R = dxhi - dxlo + 1; if (R > CAPR) R = CAPR;
    for (int i = tid; i < R * 257; i += 512) {
      int r = i / 257;
      S.u.wnd[i] = rpeb[(dxlo + r) * 257 + (i - r * 257)];
    }
    __syncthreads();

    f32x4 s0[4], s1[4];
#pragma unroll
    for (int h = 0; h < 4; ++h) {
      s0[h] = __builtin_amdgcn_mfma_f32_16x16x32_bf16(kf[h][0], qf[h], z4, 0, 0, 0);
      s1[h] = __builtin_amdgcn_mfma_f32_16x16x32_bf16(kf[h][1], qf[h], z4, 0, 0, 0);
    }
    VLD(s);
    KLD(s + 1 < 16 ? s + 1 : 15);
    LGATH(dxlo, R);

    float sv[4][8];
    float mx2 = -INFINITY;
#pragma unroll
    for (int h = 0; h < 4; ++h) {
#pragma unroll
      for (int r = 0; r < 4; ++r) {
        sv[h][r]     = fmaf(s0[h][r], SCALE_, gB[r][h]);
        sv[h][4 + r] = fmaf(s1[h][r], SCALE_, gB[4 + r][h]);
        mx2 = fmaxf(mx2, fmaxf(sv[h][r], sv[h][4 + r]));
      }
    }
    mx2 = fmaxf(mx2, __shfl_xor(mx2, 16));
    mx2 = fmaxf(mx2, __shfl_xor(mx2, 32));
    if (__any(mx2 > m_run + DTHR)) {
      float mnew = fmaxf(m_run, mx2);
      float fold = __expf(m_run - mnew);
      float fr[4];
#pragma unroll
      for (int r = 0; r < 4; ++r) fr[r] = __shfl(fold, 4 * g + r);
#pragma unroll
      for (int h = 0; h < 4; ++h) {
        l_run[h] *= fold;
#pragma unroll
        for (int dt = 0; dt < 2; ++dt)
#pragma unroll
          for (int r = 0; r < 4; ++r) aS[h][dt][r] *= fr[r];
      }
#pragma unroll
      for (int p = 0; p < 2; ++p)
#pragma unroll
        for (int dt = 0; dt < 2; ++dt)
#pragma unroll
          for (int r = 0; r < 4; ++r) aC[p][dt][r] *= fr[r];
      m_run = mnew;
    }
    s16x8 pa[4];
#pragma unroll
    for (int h = 0; h < 4; ++h) {
      float p[8], psum = 0.f;
#pragma unroll
      for (int ss = 0; ss < 8; ++ss) { p[ss] = __expf(sv[h][ss] - m_run); psum += p[ss]; }
      l_run[h] += psum;
      i32x4 pw;
#pragma unroll
      for (int c = 0; c < 4; ++c) pw[c] = (int)cvtpk(p[2 * c], p[2 * c + 1]);
      pa[h] = __builtin_bit_cast(s16x8, pw);
    }
    CKLD(s + 1 < 16 ? s + 1 : 15);

#pragma unroll
    for (int h = 0; h < 4; ++h)
#pragma unroll
      for (int dt = 0; dt < 2; ++dt)
        aS[h][dt] = __builtin_amdgcn_mfma_f32_16x16x32_bf16(pa[h], vf[h][dt], aS[h][dt], 0, 0, 0);
#pragma unroll
    for (int p = 0; p < 2; ++p)
#pragma unroll
      for (int dt = 0; dt < 2; ++dt)
        aC[p][dt] = __builtin_amdgcn_mfma_f32_16x16x32_bf16(pa[p + 2], vf[p][dt], aC[p][dt], 0, 0, 0);
  }

  // ---- merge 8 waves (r9-verbatim) ----
#pragma unroll
  for (int h = 0; h < 4; ++h) {
    l_run[h] += __shfl_xor(l_run[h], 16);
    l_run[h] += __shfl_xor(l_run[h], 32);
  }
  if (lane < 16) {
    S.mW[wv][lane] = m_run;
#pragma unroll
    for (int h = 0; h < 4; ++h) S.lW[h][wv][lane] = l_run[h];
  }
  __syncthreads();
  if (tid < 128) {
    int w = tid >> 4, q = tid & 15;
    float M = -INFINITY;
#pragma unroll
    for (int w2 = 0; w2 < 8; ++w2) M = fmaxf(M, S.mW[w2][q]);
    S.wgt[w][q] = __expf(S.mW[w][q] - M);
  }
  __syncthreads();

#pragma unroll
  for (int p = 0; p < 3; ++p)
#pragma unroll
    for (int dt = 0; dt < 2; ++dt)
#pragma unroll
      for (int r = 0; r < 4; ++r)
        S.u.acc[p][wv][4 * g + r][dt * 16 + qcol] = aS[p][dt][r];
  __syncthreads();
  const int q = tid >> 5, d = tid & 31;
  float wg[8];
#pragma unroll
  for (int w = 0; w < 8; ++w) wg[w] = S.wgt[w][q];
  float sumA[3] = {0.f, 0.f, 0.f};
#pragma unroll
  for (int p = 0; p < 3; ++p)
#pragma unroll
    for (int w = 0; w < 8; ++w) sumA[p] = fmaf(wg[w], S.u.acc[p][w][q][d], sumA[p]);
  __syncthreads();

#pragma unroll
  for (int dt = 0; dt < 2; ++dt)
#pragma unroll
    for (int r = 0; r < 4; ++r) {
      S.u.acc[0][wv][4 * g + r][dt * 16 + qcol] = aS[3][dt][r];
      S.u.acc[1][wv][4 * g + r][dt * 16 + qcol] = aC[0][dt][r];
      S.u.acc[2][wv][4 * g + r][dt * 16 + qcol] = aC[1][dt][r];
    }
  __syncthreads();
  float sumB[3] = {0.f, 0.f, 0.f};
#pragma unroll
  for (int p = 0; p < 3; ++p)
#pragma unroll
    for (int w = 0; w < 8; ++w) sumB[p] = fmaf(wg[w], S.u.acc[p][w][q][d], sumB[p]);

  float L[4];
#pragma unroll
  for (int h = 0; h < 4; ++h) {
    float ssum = 0.f;
#pragma unroll
    for (int w = 0; w < 8; ++w) ssum = fmaf(S.lW[h][w][q], S.wgt[w][q], ssum);
    L[h] = ssum;
  }
  int aorig = qperm[b * NQ_ + qg0 + q];
  float a = alpha[(size_t)b * NQ_ + aorig];
  float lam0 = S.lam[0], lam1 = S.lam[1];
  float xv0 = (1.f + a) * sumA[0] / L[0] - a * lam0 * sumB[1] / L[2];
  float xv1 = (1.f + a) * sumA[1] / L[1] - a * lam1 * sumB[2] / L[3];
  float xv2 = sumA[2] / L[2];
  float xv3 = sumB[0] / L[3];

  __syncthreads();
  S.u.xq[q][d]      = xv0;
  S.u.xq[q][32 + d] = xv1;
  S.u.xq[q][64 + d] = xv2;
  S.u.xq[q][96 + d] = xv3;
  __syncthreads();

  {
    const int j = tid & 127, rg = tid >> 7;
    float ob[4];
    float bpj = bp[j];
#pragma unroll
    for (int rr = 0; rr < 4; ++rr) ob[rr] = bpj;
#pragma unroll 4
    for (int i = 0; i < DIM_; ++i) {
      float w = Wp[i * DIM_ + j];
#pragma unroll
      for (int rr = 0; rr < 4; ++rr) ob[rr] = fmaf(S.u.xq[4 * rg + rr][i], w, ob[rr]);
    }
#pragma unroll
    for (int rr = 0; rr < 4; ++rr) {
      int orow = qperm[b * NQ_ + qg0 + 4 * rg + rr];
      out[((size_t)b * NQ_ + orow) * DIM_ + j] = ob[rr];
    }
  }
}

extern "C" void kernel_launch(void* const* d_in, const int* in_sizes, int n_in,
                              void* d_out, int out_size, void* d_ws, size_t ws_size,
                              hipStream_t stream) {
  const float* x_q   = (const float*)d_in[0];
  const float* x_kv  = (const float*)d_in[1];
  const int*   cq    = (const int*)d_in[2];
  const int*   ckc   = (const int*)d_in[3];
  const float* alpha = (const float*)d_in[4];
  const float* Wq    = (const float*)d_in[5];
  const float* bq    = (const float*)d_in[6];
  const float* Wk    = (const float*)d_in[7];
  const float* bk    = (const float*)d_in[8];
  const float* Wv    = (const float*)d_in[9];
  const float* bv    = (const float*)d_in[10];
  const float* lq1   = (const float*)d_in[11];
  const float* lk1   = (const float*)d_in[12];
  const float* lq2   = (const float*)d_in[13];
  const float* lk2   = (const float*)d_in[14];
  const float* rpe   = (const float*)d_in[15];
  const float* Wp    = (const float*)d_in[16];
  const float* bp    = (const float*)d_in[17];
  float* out = (float*)d_out;

  char* w = (char*)d_ws;
  unsigned short* Qb   = (unsigned short*)w;                   // 1 MB
  unsigned short* Kb   = (unsigned short*)(w + 1048576);       // 2 MB
  unsigned short* Vsw  = (unsigned short*)(w + 3145728);       // 2 MB
  uint2*          rpeb = (uint2*)(w + 5242880);                // 528 KB (1 MB reserved)
  int* cqs   = (int*)(w + 6291456);
  int* cks   = (int*)(w + 6356992);
  int* qperm = (int*)(w + 6422528);
  int* kperm = (int*)(w + 6488064);
  int* qrank = (int*)(w + 6553600);
  int* krank = (int*)(w + 6619136);

  prep<<<dim3(263), dim3(256), 0, stream>>>(
      cq, ckc, rpe, cqs, cks, qperm, kperm, qrank, krank, rpeb);

  qkv8g<<<dim3(1536), dim3(256), 0, stream>>>(
      x_q, x_kv, Wq, bq, Wk, bk, Wv, bv, qperm, kperm, Qb, Kb, Vsw);

  attn_win<<<dim3(B_ * (NQ_ / 16)), dim3(512), 0, stream>>>(
      Qb, Kb, Vsw, cqs, cks, qperm, alpha, rpeb, rpe,
      lq1, lk1, lq2, lk2, Wp, bp, out);
}

// Round 13
// 113.504 us; speedup vs baseline: 1.1619x; 1.1619x over previous
//
#include <hip/hip_runtime.h>
#include <hip/hip_bf16.h>

#define B_ 2
#define H_ 4
#define HD_ 32
#define NQ_ 2048
#define NKV_ 4096
#define DIM_ 128
#define SPAN_ 257
#define SCALE_ 0.17677669529663687f
#define LAMBDA_INIT_ 0.8f
#define DTHR 4.0f

typedef float f32x4 __attribute__((ext_vector_type(4)));
typedef short s16x4 __attribute__((ext_vector_type(4)));
typedef short s16x8 __attribute__((ext_vector_type(8)));
typedef int   i32x4 __attribute__((ext_vector_type(4)));
typedef float fl4   __attribute__((ext_vector_type(4)));

static __device__ __forceinline__ unsigned short f2bf(float f) {
  unsigned u = __float_as_uint(f);
  u += 0x7FFFu + ((u >> 16) & 1u);
  return (unsigned short)(u >> 16);
}
static __device__ __forceinline__ unsigned cvtpk(float lo, float hi) {
  unsigned r;
  asm("v_cvt_pk_bf16_f32 %0, %1, %2" : "=v"(r) : "v"(lo), "v"(hi));
  return r;
}

// ---------------- fused QKV projection: 8 rows/block, high block count ----------------
// grid 1536 = 512 Q-blocks (b x 256 tiles) + 1024 KV-blocks (b x 512 tiles), 256 thr.
// Q-block: 256 thr = 128 j x 2 row-halves, acc[4]. KV-block: 128 K-thr + 128 V-thr, acc[8].
// V stored transposed [B][H][HD][NKV] with the validated per-32-k swizzle:
// pos 8g+j holds k = (j<4 ? 4g+j : 16+4g+(j-4)).
__global__ __launch_bounds__(256) void qkv8(
    const float* __restrict__ xq, const float* __restrict__ xkv,
    const float* __restrict__ Wq, const float* __restrict__ bq,
    const float* __restrict__ Wk, const float* __restrict__ bk,
    const float* __restrict__ Wv, const float* __restrict__ bv,
    unsigned short* __restrict__ Qb, unsigned short* __restrict__ Kb,
    unsigned short* __restrict__ Vsw) {
  const int idx = blockIdx.x;
  const bool isq = idx < 512;
  const int b  = isq ? (idx >> 8) : ((idx - 512) >> 9);
  const int n0 = isq ? ((idx & 255) * 8) : (((idx - 512) & 511) * 8);
  const float* xsrc = isq ? xq : xkv;
  const int nlen = isq ? NQ_ : NKV_;

  __shared__ __align__(16) float xr[8][DIM_];
  const int tid = threadIdx.x;
  {
    const float* xbase = xsrc + ((size_t)b * nlen + n0) * DIM_;
    int rr = tid >> 5, c4 = tid & 31;
    *(fl4*)&xr[rr][c4 * 4] = *(const fl4*)(xbase + rr * DIM_ + c4 * 4);
  }
  __syncthreads();

  if (isq) {
    const int j = tid & 127, rh = tid >> 7;   // 4 rows: 4*rh + rr
    float acc[4];
    float bb = bq[j];
#pragma unroll
    for (int rr = 0; rr < 4; ++rr) acc[rr] = bb;
    for (int i4 = 0; i4 < 32; ++i4) {
      const float* wp = &Wq[(4 * i4) * DIM_ + j];
      float w0 = wp[0], w1 = wp[DIM_], w2 = wp[2 * DIM_], w3 = wp[3 * DIM_];
#pragma unroll
      for (int rr = 0; rr < 4; ++rr) {
        fl4 x4 = *(const fl4*)&xr[4 * rh + rr][4 * i4];
        acc[rr] = fmaf(x4[3], w3, fmaf(x4[2], w2, fmaf(x4[1], w1, fmaf(x4[0], w0, acc[rr]))));
      }
    }
    int h = j >> 5, d = j & 31;
    unsigned short* qb = Qb + (((size_t)b * H_ + h) * NQ_ + n0 + 4 * rh) * HD_ + d;
#pragma unroll
    for (int rr = 0; rr < 4; ++rr) qb[rr * HD_] = f2bf(acc[rr]);
  } else {
    const int half = tid >> 7, j = tid & 127;
    const float* W = half ? Wv : Wk;
    float bb = half ? bv[j] : bk[j];
    float acc[8];
#pragma unroll
    for (int rr = 0; rr < 8; ++rr) acc[rr] = bb;
    for (int i4 = 0; i4 < 32; ++i4) {
      const float* wp = &W[(4 * i4) * DIM_ + j];
      float w0 = wp[0], w1 = wp[DIM_], w2 = wp[2 * DIM_], w3 = wp[3 * DIM_];
#pragma unroll
      for (int rr = 0; rr < 8; ++rr) {
        fl4 x4 = *(const fl4*)&xr[rr][4 * i4];
        acc[rr] = fmaf(x4[3], w3, fmaf(x4[2], w2, fmaf(x4[1], w1, fmaf(x4[0], w0, acc[rr]))));
      }
    }
    int h = j >> 5, d = j & 31;
    if (half == 0) {
      unsigned short* kb2 = Kb + (((size_t)b * H_ + h) * NKV_ + n0) * HD_ + d;
#pragma unroll
      for (int rr = 0; rr < 8; ++rr) kb2[rr * HD_] = f2bf(acc[rr]);
    } else {
      unsigned short* vb = Vsw + (((size_t)b * H_ + h) * HD_ + d) * NKV_ + (n0 & ~31);
      const int base = n0 & 31;   // 0, 8, 16, or 24
#pragma unroll
      for (int c = 0; c < 2; ++c) {
        int k0r = base + 4 * c;
        int posb = (k0r < 16) ? 8 * (k0r >> 2) : 8 * ((k0r - 16) >> 2) + 4;
        s16x4 t4;
#pragma unroll
        for (int e = 0; e < 4; ++e) t4[e] = (short)f2bf(acc[4 * c + e]);
        *(s16x4*)(vb + posb) = t4;
      }
    }
  }
}

// ---------------- barrier-free differential flash-attention + out-proj ----------------
// (r5/r8/r9-validated, verbatim) grid 256 = b(2) x qtile(128 of 16 q-rows), 512 thr = 8 waves.
__global__ __launch_bounds__(512) void attn_nb(
    const unsigned short* __restrict__ Qg, const unsigned short* __restrict__ Kg,
    const unsigned short* __restrict__ Vg, const int* __restrict__ cq,
    const int* __restrict__ ck, const float* __restrict__ alpha,
    const float* __restrict__ rpe, const float* __restrict__ lq1,
    const float* __restrict__ lk1, const float* __restrict__ lq2,
    const float* __restrict__ lk2, const float* __restrict__ Wp,
    const float* __restrict__ bp, float* __restrict__ out) {

  const int tid = threadIdx.x;
  const int lane = tid & 63;
  const int wv = tid >> 6;
  const int qcol = lane & 15;
  const int g = lane >> 4;
  const int qt = blockIdx.x & 127;
  const int b = blockIdx.x >> 7;
  const int qg0 = qt * 16;
  const int k_base = wv * 512;

  __shared__ struct {
    union {
      float acc[3][8][16][36];
      float xq[16][128];
    } u;
    float mW[8][17];
    float lW[4][8][17];
    float wgt[8][17];
    float lam[2];
  } S;

  if (tid < 2) {
    float s1 = 0.f, s2 = 0.f;
    for (int d = 0; d < HD_; ++d) {
      s1 += lq1[tid * HD_ + d] * lk1[tid * HD_ + d];
      s2 += lq2[tid * HD_ + d] * lk2[tid * HD_ + d];
    }
    S.lam[tid] = __expf(s1) - __expf(s2) + LAMBDA_INIT_;
  }

  s16x8 qf[4];
#pragma unroll
  for (int h = 0; h < 4; ++h)
    qf[h] = *(const s16x8*)(Qg + (((size_t)b * H_ + h) * NQ_ + qg0 + qcol) * HD_ + 8 * g);

  const int2 cqv = ((const int2*)cq)[(size_t)b * NQ_ + qg0 + qcol];
  const int qx = cqv.x + 128, qy = cqv.y + 128;

  const unsigned short* kb[4];
  const unsigned short* vp[4][2];
#pragma unroll
  for (int h = 0; h < 4; ++h) {
    kb[h] = Kg + (((size_t)b * H_ + h) * NKV_ + k_base) * HD_;
#pragma unroll
    for (int dt = 0; dt < 2; ++dt)
      vp[h][dt] = Vg + (((size_t)b * H_ + h) * HD_ + dt * 16 + qcol) * NKV_ + k_base + 8 * g;
  }
  int koff[2];
#pragma unroll
  for (int t = 0; t < 2; ++t) koff[t] = (16 * t + qcol) * HD_ + 8 * g;

  const i32x4* ck4 = (const i32x4*)ck + (((size_t)b * NKV_ + k_base) >> 1);
  const fl4* __restrict__ rpe4 = (const fl4*)rpe;

  float m_run = -INFINITY;
  float l_run[4] = {0.f, 0.f, 0.f, 0.f};
  f32x4 z4 = {0.f, 0.f, 0.f, 0.f};
  f32x4 aS[4][2], aC[2][2];
#pragma unroll
  for (int h = 0; h < 4; ++h) { aS[h][0] = z4; aS[h][1] = z4; }
#pragma unroll
  for (int p = 0; p < 2; ++p) { aC[p][0] = z4; aC[p][1] = z4; }

  s16x8 kf[4][2], vf[4][2];
  i32x4 ckt[4];
  fl4 gB[8];

#define CKLD(ST) {                                                         \
    const int s_ = (ST);                                                   \
    _Pragma("unroll") for (int t = 0; t < 2; ++t)                          \
    _Pragma("unroll") for (int hf = 0; hf < 2; ++hf)                       \
      ckt[2 * t + hf] = ck4[s_ * 16 + 8 * t + 2 * g + hf];                 \
  }
#define KLD(ST) {                                                          \
    const int s_ = (ST);                                                   \
    _Pragma("unroll") for (int h = 0; h < 4; ++h)                          \
    _Pragma("unroll") for (int t = 0; t < 2; ++t)                          \
      kf[h][t] = *(const s16x8*)(kb[h] + s_ * 32 * HD_ + koff[t]);         \
  }
#define VLD(ST) {                                                          \
    const int s_ = (ST);                                                   \
    _Pragma("unroll") for (int h = 0; h < 4; ++h)                          \
    _Pragma("unroll") for (int dt = 0; dt < 2; ++dt)                       \
      vf[h][dt] = *(const s16x8*)(vp[h][dt] + s_ * 32);                    \
  }
#define GATH() {                                                           \
    _Pragma("unroll") for (int t = 0; t < 2; ++t)                          \
    _Pragma("unroll") for (int hf = 0; hf < 2; ++hf) {                     \
      i32x4 cc = ckt[2 * t + hf];                                          \
      int dx0 = qx - cc[0]; dx0 = dx0 < 0 ? 0 : (dx0 > 256 ? 256 : dx0);   \
      int dy0 = qy - cc[1]; dy0 = dy0 < 0 ? 0 : (dy0 > 256 ? 256 : dy0);   \
      gB[4 * t + 2 * hf] = rpe4[dx0 * SPAN_ + dy0];                        \
      int dx1 = qx - cc[2]; dx1 = dx1 < 0 ? 0 : (dx1 > 256 ? 256 : dx1);   \
      int dy1 = qy - cc[3]; dy1 = dy1 < 0 ? 0 : (dy1 > 256 ? 256 : dy1);   \
      gB[4 * t + 2 * hf + 1] = rpe4[dx1 * SPAN_ + dy1];                    \
    }                                                                      \
  }

  CKLD(0);
  KLD(0);
  GATH();
  CKLD(1);

  for (int st = 0; st < 16; ++st) {
    f32x4 s0[4], s1[4];
#pragma unroll
    for (int h = 0; h < 4; ++h) {
      s0[h] = __builtin_amdgcn_mfma_f32_16x16x32_bf16(kf[h][0], qf[h], z4, 0, 0, 0);
      s1[h] = __builtin_amdgcn_mfma_f32_16x16x32_bf16(kf[h][1], qf[h], z4, 0, 0, 0);
    }
    VLD(st);
    KLD(st + 1 < 16 ? st + 1 : 15);

    float sv[4][8];
    float mx = -INFINITY;
#pragma unroll
    for (int h = 0; h < 4; ++h) {
#pragma unroll
      for (int r = 0; r < 4; ++r) {
        sv[h][r]     = fmaf(s0[h][r], SCALE_, gB[r][h]);
        sv[h][4 + r] = fmaf(s1[h][r], SCALE_, gB[4 + r][h]);
        mx = fmaxf(mx, fmaxf(sv[h][r], sv[h][4 + r]));
      }
    }
    mx = fmaxf(mx, __shfl_xor(mx, 16));
    mx = fmaxf(mx, __shfl_xor(mx, 32));
    if (__any(mx > m_run + DTHR)) {
      float mnew = fmaxf(m_run, mx);
      float fold = __expf(m_run - mnew);
      float fr[4];
#pragma unroll
      for (int r = 0; r < 4; ++r) fr[r] = __shfl(fold, 4 * g + r);
#pragma unroll
      for (int h = 0; h < 4; ++h) {
        l_run[h] *= fold;
#pragma unroll
        for (int dt = 0; dt < 2; ++dt)
#pragma unroll
          for (int r = 0; r < 4; ++r) aS[h][dt][r] *= fr[r];
      }
#pragma unroll
      for (int p = 0; p < 2; ++p)
#pragma unroll
        for (int dt = 0; dt < 2; ++dt)
#pragma unroll
          for (int r = 0; r < 4; ++r) aC[p][dt][r] *= fr[r];
      m_run = mnew;
    }
    s16x8 pa[4];
#pragma unroll
    for (int h = 0; h < 4; ++h) {
      float p[8], psum = 0.f;
#pragma unroll
      for (int s = 0; s < 8; ++s) { p[s] = __expf(sv[h][s] - m_run); psum += p[s]; }
      l_run[h] += psum;
      i32x4 pw;
#pragma unroll
      for (int c = 0; c < 4; ++c) pw[c] = (int)cvtpk(p[2 * c], p[2 * c + 1]);
      pa[h] = __builtin_bit_cast(s16x8, pw);
    }
    GATH();
    CKLD(st + 2 < 16 ? st + 2 : 15);

#pragma unroll
    for (int h = 0; h < 4; ++h)
#pragma unroll
      for (int dt = 0; dt < 2; ++dt)
        aS[h][dt] = __builtin_amdgcn_mfma_f32_16x16x32_bf16(pa[h], vf[h][dt], aS[h][dt], 0, 0, 0);
#pragma unroll
    for (int p = 0; p < 2; ++p)
#pragma unroll
      for (int dt = 0; dt < 2; ++dt)
        aC[p][dt] = __builtin_amdgcn_mfma_f32_16x16x32_bf16(pa[p + 2], vf[p][dt], aC[p][dt], 0, 0, 0);
  }

  // ---- merge 8 k-slice waves ----
#pragma unroll
  for (int h = 0; h < 4; ++h) {
    l_run[h] += __shfl_xor(l_run[h], 16);
    l_run[h] += __shfl_xor(l_run[h], 32);
  }
  if (lane < 16) {
    S.mW[wv][lane] = m_run;
#pragma unroll
    for (int h = 0; h < 4; ++h) S.lW[h][wv][lane] = l_run[h];
  }
  __syncthreads();
  if (tid < 128) {
    int w = tid >> 4, q = tid & 15;
    float M = -INFINITY;
#pragma unroll
    for (int w2 = 0; w2 < 8; ++w2) M = fmaxf(M, S.mW[w2][q]);
    S.wgt[w][q] = __expf(S.mW[w][q] - M);
  }
  __syncthreads();

  // phase A: planes aS[0..2]
#pragma unroll
  for (int p = 0; p < 3; ++p)
#pragma unroll
    for (int dt = 0; dt < 2; ++dt)
#pragma unroll
      for (int r = 0; r < 4; ++r)
        S.u.acc[p][wv][4 * g + r][dt * 16 + qcol] = aS[p][dt][r];
  __syncthreads();
  const int q = tid >> 5, d = tid & 31;
  float wg[8];
#pragma unroll
  for (int w = 0; w < 8; ++w) wg[w] = S.wgt[w][q];
  float sumA[3] = {0.f, 0.f, 0.f};
#pragma unroll
  for (int p = 0; p < 3; ++p)
#pragma unroll
    for (int w = 0; w < 8; ++w) sumA[p] = fmaf(wg[w], S.u.acc[p][w][q][d], sumA[p]);
  __syncthreads();

  // phase B: planes aS[3], aC[0], aC[1]
#pragma unroll
  for (int dt = 0; dt < 2; ++dt)
#pragma unroll
    for (int r = 0; r < 4; ++r) {
      S.u.acc[0][wv][4 * g + r][dt * 16 + qcol] = aS[3][dt][r];
      S.u.acc[1][wv][4 * g + r][dt * 16 + qcol] = aC[0][dt][r];
      S.u.acc[2][wv][4 * g + r][dt * 16 + qcol] = aC[1][dt][r];
    }
  __syncthreads();
  float sumB[3] = {0.f, 0.f, 0.f};
#pragma unroll
  for (int p = 0; p < 3; ++p)
#pragma unroll
    for (int w = 0; w < 8; ++w) sumB[p] = fmaf(wg[w], S.u.acc[p][w][q][d], sumB[p]);

  float L[4];
#pragma unroll
  for (int h = 0; h < 4; ++h) {
    float s = 0.f;
#pragma unroll
    for (int w = 0; w < 8; ++w) s = fmaf(S.lW[h][w][q], S.wgt[w][q], s);
    L[h] = s;
  }
  float a = alpha[(size_t)b * NQ_ + qg0 + q];
  float lam0 = S.lam[0], lam1 = S.lam[1];
  float xv0 = (1.f + a) * sumA[0] / L[0] - a * lam0 * sumB[1] / L[2];
  float xv1 = (1.f + a) * sumA[1] / L[1] - a * lam1 * sumB[2] / L[3];
  float xv2 = sumA[2] / L[2];
  float xv3 = sumB[0] / L[3];

  // ---- fused output projection: out = xq @ Wp + bp ----
  __syncthreads();  // phase-B acc reads complete; safe to overlay xq
  S.u.xq[q][d]      = xv0;
  S.u.xq[q][32 + d] = xv1;
  S.u.xq[q][64 + d] = xv2;
  S.u.xq[q][96 + d] = xv3;
  __syncthreads();

  {
    const int j = tid & 127, rg = tid >> 7;   // rg in [0,4): rows 4rg..4rg+3
    float ob[4];
    float bpj = bp[j];
#pragma unroll
    for (int rr = 0; rr < 4; ++rr) ob[rr] = bpj;
#pragma unroll 4
    for (int i = 0; i < DIM_; ++i) {
      float w = Wp[i * DIM_ + j];
#pragma unroll
      for (int rr = 0; rr < 4; ++rr) ob[rr] = fmaf(S.u.xq[4 * rg + rr][i], w, ob[rr]);
    }
#pragma unroll
    for (int rr = 0; rr < 4; ++rr)
      out[((size_t)b * NQ_ + qg0 + 4 * rg + rr) * DIM_ + j] = ob[rr];
  }
}

extern "C" void kernel_launch(void* const* d_in, const int* in_sizes, int n_in,
                              void* d_out, int out_size, void* d_ws, size_t ws_size,
                              hipStream_t stream) {
  const float* x_q   = (const float*)d_in[0];
  const float* x_kv  = (const float*)d_in[1];
  const int*   cq    = (const int*)d_in[2];
  const int*   ckc   = (const int*)d_in[3];
  const float* alpha = (const float*)d_in[4];
  const float* Wq    = (const float*)d_in[5];
  const float* bq    = (const float*)d_in[6];
  const float* Wk    = (const float*)d_in[7];
  const float* bk    = (const float*)d_in[8];
  const float* Wv    = (const float*)d_in[9];
  const float* bv    = (const float*)d_in[10];
  const float* lq1   = (const float*)d_in[11];
  const float* lk1   = (const float*)d_in[12];
  const float* lq2   = (const float*)d_in[13];
  const float* lk2   = (const float*)d_in[14];
  const float* rpe   = (const float*)d_in[15];
  const float* Wp    = (const float*)d_in[16];
  const float* bp    = (const float*)d_in[17];
  float* out = (float*)d_out;

  char* w = (char*)d_ws;
  unsigned short* Qb  = (unsigned short*)w;                    // 1 MB
  unsigned short* Kb  = (unsigned short*)(w + 1048576);        // 2 MB
  unsigned short* Vsw = (unsigned short*)(w + 3145728);        // 2 MB

  qkv8<<<dim3(1536), dim3(256), 0, stream>>>(
      x_q, x_kv, Wq, bq, Wk, bk, Wv, bv, Qb, Kb, Vsw);

  attn_nb<<<dim3(B_ * (NQ_ / 16)), dim3(512), 0, stream>>>(
      Qb, Kb, Vsw, cq, ckc, alpha, rpe, lq1, lk1, lq2, lk2, Wp, bp, out);
}